// Round 1
// baseline (576.610 us; speedup 1.0000x reference)
//
#include <hip/hip_runtime.h>
#include <cstdint>
#include <cstddef>

// B=16, C=512, H=W=64, HW=4096, C8=64, C2=256, M(keys)=1024

typedef float f32x4 __attribute__((ext_vector_type(4)));
typedef short bf16x8 __attribute__((ext_vector_type(8)));

static __device__ __forceinline__ float max4f(float a, float b, float c, float d) {
  return fmaxf(fmaxf(a, b), fmaxf(c, d));
}

static __device__ __forceinline__ unsigned short f2bf(float f) {
  unsigned int u = __float_as_uint(f);
  unsigned int r = u + 0x7fffu + ((u >> 16) & 1u);  // RNE
  return (unsigned short)(r >> 16);
}

// async 16B/lane global->LDS copy; lds base must be wave-uniform, HW scatters lane*16
static __device__ __forceinline__ void async_ld16(void* lds, const void* g) {
  __builtin_amdgcn_global_load_lds(
      (const __attribute__((address_space(1))) unsigned int*)g,
      (__attribute__((address_space(3))) unsigned int*)lds, 16, 0, 0);
}

// ---------------- pack weights: Wcat_bf [384][512], bcat[384] fp32, Wa_bf [512][256] ----------------
__global__ __launch_bounds__(256) void pack_kernel(
    const float* __restrict__ wt, const float* __restrict__ bt,
    const float* __restrict__ wp, const float* __restrict__ bp,
    const float* __restrict__ wg, const float* __restrict__ bg,
    const float* __restrict__ wa,
    unsigned short* __restrict__ Wcat_bf, float* __restrict__ bcat,
    unsigned short* __restrict__ Wa_bf) {
  int i = blockIdx.x * 256 + threadIdx.x;
  if (i < 384 * 512) {
    int o = i >> 9, k = i & 511;
    float v;
    if (o < 64)       v = wt[o * 512 + k];
    else if (o < 128) v = wp[(o - 64) * 512 + k];
    else              v = wg[(o - 128) * 512 + k];
    Wcat_bf[i] = f2bf(v);
  }
  if (i < 512 * 256) Wa_bf[i] = f2bf(wa[i]);
  if (i < 384) {
    float v;
    if (i < 64)       v = bt[i];
    else if (i < 128) v = bp[i - 64];
    else              v = bg[i - 128];
    bcat[i] = v;
  }
}

// ---------------- transpose/convert: X fp32 [B][512][4096] -> Xbf_T bf16 [B][4096][512] ----------------
__global__ __launch_bounds__(256) void transpose_kernel(
    const float* __restrict__ X, unsigned short* __restrict__ Xbf_T) {
  __shared__ unsigned short smT[64 * 516];
  const int b = blockIdx.y, n0 = blockIdx.x * 64;
  const int t = threadIdx.x;
  const float* Xb = X + (size_t)b * 512 * 4096;

  {
    const int nq = t & 15, kr = t >> 4;
#pragma unroll 4
    for (int it = 0; it < 32; ++it) {
      int k = it * 16 + kr;
      float4 v = *(const float4*)&Xb[(size_t)k * 4096 + n0 + nq * 4];
      smT[(nq * 4 + 0) * 516 + k] = f2bf(v.x);
      smT[(nq * 4 + 1) * 516 + k] = f2bf(v.y);
      smT[(nq * 4 + 2) * 516 + k] = f2bf(v.z);
      smT[(nq * 4 + 3) * 516 + k] = f2bf(v.w);
    }
  }
  __syncthreads();
  {
    const int c = t & 63, w = t >> 6;
#pragma unroll 4
    for (int i = 0; i < 16; ++i) {
      int n = w + 4 * i;
      const unsigned short* src = &smT[n * 516 + c * 8];
      uint2 lo = *(const uint2*)&src[0];
      uint2 hi = *(const uint2*)&src[4];
      uint4 v; v.x = lo.x; v.y = lo.y; v.z = hi.x; v.w = hi.y;
      *(uint4*)&Xbf_T[((size_t)b * 4096 + n0 + n) * 512 + c * 8] = v;
    }
  }
}

// ---------------- conv GEMM (bf16 MFMA, LDS-staged) + fused maxpool epilogue ----------------
// C[384 m][4096 n] = Wcat @ X; tile 128x128, BK=32, single-buffer global_load_lds staging.
__global__ __launch_bounds__(256, 3) void conv_pool_kernel(
    const unsigned short* __restrict__ Xbf_T, const unsigned short* __restrict__ Wcat_bf,
    const float* __restrict__ bcat,
    unsigned short* __restrict__ theta_t, unsigned short* __restrict__ phi_t,
    unsigned short* __restrict__ g_t) {
  const int b = blockIdx.z, mt = blockIdx.y, nt = blockIdx.x;
  const int n0 = nt * 128;
  __shared__ union {
    struct { unsigned short A[128 * 32]; unsigned short B[128 * 32]; } st;  // 8KB + 8KB
    float cs[64][132];                                                      // 33.8KB
  } sm;
  const int t = threadIdx.x;
  const int wave = t >> 6, lane = t & 63;
  const int wm = wave >> 1, wn = wave & 1;
  const int l16 = lane & 15, quad = lane >> 4;
  const int srow = lane >> 2, skq = (lane & 3) * 8;

  const unsigned short* gA = Wcat_bf + (size_t)(mt * 128) * 512 + skq;
  const unsigned short* gB = Xbf_T + ((size_t)b * 4096 + n0) * 512 + skq;
  const int r0 = wave * 32;

  f32x4 acc[4][4];
#pragma unroll
  for (int i = 0; i < 4; ++i)
#pragma unroll
    for (int j = 0; j < 4; ++j) acc[i][j] = (f32x4)(0.f);

  const int abase = (wm * 64 + l16) * 32 + quad * 8;
  const int bbase = (wn * 64 + l16) * 32 + quad * 8;

  for (int k0 = 0; k0 < 512; k0 += 32) {
    __syncthreads();  // prior frag reads done before overwrite
    async_ld16(&sm.st.A[(r0) * 32],      gA + (size_t)(r0 + srow) * 512 + k0);
    async_ld16(&sm.st.A[(r0 + 16) * 32], gA + (size_t)(r0 + 16 + srow) * 512 + k0);
    async_ld16(&sm.st.B[(r0) * 32],      gB + (size_t)(r0 + srow) * 512 + k0);
    async_ld16(&sm.st.B[(r0 + 16) * 32], gB + (size_t)(r0 + 16 + srow) * 512 + k0);
    __syncthreads();  // vmcnt drain -> staged data visible
    bf16x8 af[4], bfr[4];
#pragma unroll
    for (int am = 0; am < 4; ++am) af[am] = *(const bf16x8*)&sm.st.A[abase + am * 16 * 32];
#pragma unroll
    for (int bn = 0; bn < 4; ++bn) bfr[bn] = *(const bf16x8*)&sm.st.B[bbase + bn * 16 * 32];
#pragma unroll
    for (int am = 0; am < 4; ++am)
#pragma unroll
      for (int bn = 0; bn < 4; ++bn)
        acc[am][bn] = __builtin_amdgcn_mfma_f32_16x16x32_bf16(af[am], bfr[bn], acc[am][bn], 0, 0, 0);
  }
  __syncthreads();  // staging buffers dead; cs reuse safe

  // epilogue: two 64-row stripes through LDS
  for (int s = 0; s < 2; ++s) {
    const int m0 = mt * 128 + s * 64;
    if (wm == s) {
#pragma unroll
      for (int am = 0; am < 4; ++am)
#pragma unroll
        for (int bn = 0; bn < 4; ++bn)
#pragma unroll
          for (int reg = 0; reg < 4; ++reg)
            sm.cs[am * 16 + quad * 4 + reg][wn * 64 + bn * 16 + l16] =
                acc[am][bn][reg] + bcat[m0 + am * 16 + quad * 4 + reg];
    }
    __syncthreads();
    if (m0 < 64) {  // theta: -> [B][4096][64] bf16
      int col = t >> 1, half = t & 1;
      unsigned short vals[32];
#pragma unroll
      for (int i = 0; i < 32; ++i) vals[i] = f2bf(sm.cs[half * 32 + i][col]);
      unsigned short* dst = theta_t + ((size_t)b * 4096 + n0 + col) * 64 + half * 32;
#pragma unroll
      for (int j = 0; j < 4; ++j) ((uint4*)dst)[j] = ((const uint4*)vals)[j];
    } else if (m0 < 128) {  // phi: 2x2 pool -> [B][1024][64] bf16
      int px = t >> 3, ch0 = (t & 7) * 8;
      unsigned short v[8];
#pragma unroll
      for (int j = 0; j < 8; ++j) {
        int ch = ch0 + j;
        v[j] = f2bf(max4f(sm.cs[ch][2 * px], sm.cs[ch][2 * px + 1],
                          sm.cs[ch][64 + 2 * px], sm.cs[ch][64 + 2 * px + 1]));
      }
      *(uint4*)&phi_t[((size_t)b * 1024 + nt * 32 + px) * 64 + ch0] = *(const uint4*)v;
    } else {  // g: 2x2 pool -> [B][256][1024] bf16 (c-major)
      int ch = t >> 2, px0 = (t & 3) * 8;
      int gc = m0 - 128 + ch;
      unsigned short v[8];
#pragma unroll
      for (int j = 0; j < 8; ++j) {
        int px = px0 + j;
        v[j] = f2bf(max4f(sm.cs[ch][2 * px], sm.cs[ch][2 * px + 1],
                          sm.cs[ch][64 + 2 * px], sm.cs[ch][64 + 2 * px + 1]));
      }
      *(uint4*)&g_t[((size_t)b * 256 + gc) * 1024 + nt * 32 + px0] = *(const uint4*)v;
    }
    __syncthreads();
  }
}

// ---------------- fused MFMA attention: 512 threads, 8 waves ----------------
// wave w: QK over keys [128w,128w+128) for 32 queries; single stats barrier;
// P (normalized) -> bf16 LDS; PV over c-slice [32w,32w+32) x all 1024 keys.
// PV is 2-stage software-pipelined: next 64 keys' S/g fragments issued before
// the current 8-MFMA cluster (covers L2 latency; MfmaUtil was 10%).
__global__ __launch_bounds__(512, 4) void attn_kernel(
    const unsigned short* __restrict__ theta, const unsigned short* __restrict__ phi,
    const unsigned short* __restrict__ g, unsigned short* __restrict__ Obf) {
  const int b = blockIdx.y, q0 = blockIdx.x * 32;
  __shared__ unsigned short S_s[32][1032];  // 66 KB
  __shared__ float2 sstat[32][8];           // (m_w, sum_w) per q-row per wave
  const int t = threadIdx.x;
  const int w = t >> 6, lane = t & 63;
  const int l16 = lane & 15, quad = lane >> 4;
  const int m0w = w * 128;

  // A-frags: theta[32 q][64 c]
  bf16x8 afrag[2][2];
#pragma unroll
  for (int qt = 0; qt < 2; ++qt)
#pragma unroll
    for (int kh = 0; kh < 2; ++kh)
      afrag[qt][kh] = *(const bf16x8*)&theta[((size_t)b * 4096 + q0 + qt * 16 + l16) * 64 +
                                             kh * 32 + quad * 8];

  // ---- QK^T: S[32 q][128 m] per wave, 1-ahead phi prefetch ----
  f32x4 acc[2][8];
#pragma unroll
  for (int qt = 0; qt < 2; ++qt)
#pragma unroll
    for (int mt = 0; mt < 8; ++mt) acc[qt][mt] = (f32x4)(0.f);

  const unsigned short* phiW = phi + (size_t)b * 1024 * 64 + (size_t)(m0w + l16) * 64 + quad * 8;
  bf16x8 pb0 = *(const bf16x8*)&phiW[0];
  bf16x8 pb1 = *(const bf16x8*)&phiW[32];
#pragma unroll
  for (int mt = 0; mt < 8; ++mt) {
    const int nmt = (mt < 7) ? mt + 1 : 7;
    bf16x8 nb0 = *(const bf16x8*)&phiW[(size_t)nmt * 16 * 64];
    bf16x8 nb1 = *(const bf16x8*)&phiW[(size_t)nmt * 16 * 64 + 32];
    __builtin_amdgcn_s_setprio(1);
    acc[0][mt] = __builtin_amdgcn_mfma_f32_16x16x32_bf16(afrag[0][0], pb0, acc[0][mt], 0, 0, 0);
    acc[1][mt] = __builtin_amdgcn_mfma_f32_16x16x32_bf16(afrag[1][0], pb0, acc[1][mt], 0, 0, 0);
    acc[0][mt] = __builtin_amdgcn_mfma_f32_16x16x32_bf16(afrag[0][1], pb1, acc[0][mt], 0, 0, 0);
    acc[1][mt] = __builtin_amdgcn_mfma_f32_16x16x32_bf16(afrag[1][1], pb1, acc[1][mt], 0, 0, 0);
    __builtin_amdgcn_s_setprio(0);
    pb0 = nb0; pb1 = nb1;
  }

  // ---- per-wave max & exp-sum (rows: q = qt*16 + quad*4 + reg) ----
  float mx8[8], sum8[8];
#pragma unroll
  for (int r = 0; r < 8; ++r) {
    int qt = r >> 2, reg = r & 3;
    float m = acc[qt][0][reg];
#pragma unroll
    for (int mt = 1; mt < 8; ++mt) m = fmaxf(m, acc[qt][mt][reg]);
#pragma unroll
    for (int d = 1; d < 16; d <<= 1) m = fmaxf(m, __shfl_xor(m, d));
    mx8[r] = m;
    sum8[r] = 0.f;
  }
#pragma unroll
  for (int qt = 0; qt < 2; ++qt)
#pragma unroll
    for (int mt = 0; mt < 8; ++mt)
#pragma unroll
      for (int reg = 0; reg < 4; ++reg) {
        int r = qt * 4 + reg;
        float p = __expf(acc[qt][mt][reg] - mx8[r]);
        acc[qt][mt][reg] = p;
        sum8[r] += p;
      }
#pragma unroll
  for (int r = 0; r < 8; ++r) {
#pragma unroll
    for (int d = 1; d < 16; d <<= 1) sum8[r] += __shfl_xor(sum8[r], d);
  }
  if (l16 == 0) {
#pragma unroll
    for (int r = 0; r < 8; ++r) {
      int q = (r >> 2) * 16 + quad * 4 + (r & 3);
      sstat[q][w] = make_float2(mx8[r], sum8[r]);
    }
  }
  __syncthreads();  // single stats barrier

  // ---- global stats + normalized P write ----
  float alpha[8];
#pragma unroll
  for (int r = 0; r < 8; ++r) {
    int q = (r >> 2) * 16 + quad * 4 + (r & 3);
    float2 st[8];
#pragma unroll
    for (int j = 0; j < 4; ++j) ((float4*)st)[j] = *(const float4*)&sstat[q][j * 2];
    float mg = st[0].x;
#pragma unroll
    for (int j = 1; j < 8; ++j) mg = fmaxf(mg, st[j].x);
    float sg = 0.f;
#pragma unroll
    for (int j = 0; j < 8; ++j) sg += st[j].y * __expf(st[j].x - mg);
    alpha[r] = __expf(mx8[r] - mg) / sg;
  }
#pragma unroll
  for (int qt = 0; qt < 2; ++qt)
#pragma unroll
    for (int mt = 0; mt < 8; ++mt)
#pragma unroll
      for (int reg = 0; reg < 4; ++reg) {
        int q = qt * 16 + quad * 4 + reg;
        S_s[q][m0w + mt * 16 + l16] = f2bf(acc[qt][mt][reg] * alpha[qt * 4 + reg]);
      }
  __syncthreads();

  // ---- PV: O[32 q][32 c] per wave over all 1024 keys, 2-stage pipeline ----
  const int cbase = w * 32;
  f32x4 accO[2][2];
#pragma unroll
  for (int qt = 0; qt < 2; ++qt)
#pragma unroll
    for (int ct = 0; ct < 2; ++ct) accO[qt][ct] = (f32x4)(0.f);

  const unsigned short* gB = g + (size_t)b * 256 * 1024;
  const unsigned short* gR0 = gB + (size_t)(cbase + l16) * 1024 + quad * 8;
  const unsigned short* gR1 = gB + (size_t)(cbase + 16 + l16) * 1024 + quad * 8;
  const unsigned short* sR0 = &S_s[l16][quad * 8];
  const unsigned short* sR1 = &S_s[16 + l16][quad * 8];

  // stage a = keys [k0, k0+32), stage b = keys [k0+32, k0+64)
  bf16x8 Aa0 = *(const bf16x8*)&sR0[0],  Aa1 = *(const bf16x8*)&sR1[0];
  bf16x8 Ba0 = *(const bf16x8*)&gR0[0],  Ba1 = *(const bf16x8*)&gR1[0];
  bf16x8 Ab0 = *(const bf16x8*)&sR0[32], Ab1 = *(const bf16x8*)&sR1[32];
  bf16x8 Bb0 = *(const bf16x8*)&gR0[32], Bb1 = *(const bf16x8*)&gR1[32];

  for (int k0 = 0; k0 < 1024; k0 += 64) {
    const int kn0 = (k0 + 64 < 1024) ? k0 + 64 : 0;   // clamped dummy on tail
    const int kn1 = (k0 + 96 < 1024) ? k0 + 96 : 0;
    // issue next 64 keys' fragments before the MFMA cluster
    bf16x8 An0 = *(const bf16x8*)&sR0[kn0], An1 = *(const bf16x8*)&sR1[kn0];
    bf16x8 Bn0 = *(const bf16x8*)&gR0[kn0], Bn1 = *(const bf16x8*)&gR1[kn0];
    bf16x8 Am0 = *(const bf16x8*)&sR0[kn1], Am1 = *(const bf16x8*)&sR1[kn1];
    bf16x8 Bm0 = *(const bf16x8*)&gR0[kn1], Bm1 = *(const bf16x8*)&gR1[kn1];
    __builtin_amdgcn_s_setprio(1);
    accO[0][0] = __builtin_amdgcn_mfma_f32_16x16x32_bf16(Aa0, Ba0, accO[0][0], 0, 0, 0);
    accO[0][1] = __builtin_amdgcn_mfma_f32_16x16x32_bf16(Aa0, Ba1, accO[0][1], 0, 0, 0);
    accO[1][0] = __builtin_amdgcn_mfma_f32_16x16x32_bf16(Aa1, Ba0, accO[1][0], 0, 0, 0);
    accO[1][1] = __builtin_amdgcn_mfma_f32_16x16x32_bf16(Aa1, Ba1, accO[1][1], 0, 0, 0);
    accO[0][0] = __builtin_amdgcn_mfma_f32_16x16x32_bf16(Ab0, Bb0, accO[0][0], 0, 0, 0);
    accO[0][1] = __builtin_amdgcn_mfma_f32_16x16x32_bf16(Ab0, Bb1, accO[0][1], 0, 0, 0);
    accO[1][0] = __builtin_amdgcn_mfma_f32_16x16x32_bf16(Ab1, Bb0, accO[1][0], 0, 0, 0);
    accO[1][1] = __builtin_amdgcn_mfma_f32_16x16x32_bf16(Ab1, Bb1, accO[1][1], 0, 0, 0);
    __builtin_amdgcn_s_setprio(0);
    Aa0 = An0; Aa1 = An1; Ba0 = Bn0; Ba1 = Bn1;
    Ab0 = Am0; Ab1 = Am1; Bb0 = Bm0; Bb1 = Bm1;
  }

  unsigned short* Ob = Obf + ((size_t)b * 4096 + q0) * 256;
#pragma unroll
  for (int qt = 0; qt < 2; ++qt)
#pragma unroll
    for (int ct = 0; ct < 2; ++ct)
#pragma unroll
      for (int reg = 0; reg < 4; ++reg)
        Ob[(size_t)(qt * 16 + quad * 4 + reg) * 256 + cbase + ct * 16 + l16] =
            f2bf(accO[qt][ct][reg]);
}

// ---------------- final conv (bf16 MFMA, LDS-staged) + residual ----------------
__global__ __launch_bounds__(256, 3) void out_kernel(
    const float* __restrict__ X, const unsigned short* __restrict__ Obf,
    const unsigned short* __restrict__ Wa_bf, const float* __restrict__ ba,
    const float* __restrict__ sigma, float* __restrict__ out) {
  const int b = blockIdx.z, mt = blockIdx.y, nt = blockIdx.x;
  __shared__ struct { unsigned short A[128 * 32]; unsigned short B[128 * 32]; } sm;
  const int t = threadIdx.x;
  const int wave = t >> 6, lane = t & 63;
  const int wm = wave >> 1, wn = wave & 1;
  const int l16 = lane & 15, quad = lane >> 4;
  const int srow = lane >> 2, skq = (lane & 3) * 8;

  const unsigned short* gA = Wa_bf + (size_t)(mt * 128) * 256 + skq;
  const unsigned short* gB = Obf + ((size_t)b * 4096 + nt * 128) * 256 + skq;
  const int r0 = wave * 32;

  f32x4 acc[4][4];
#pragma unroll
  for (int i = 0; i < 4; ++i)
#pragma unroll
    for (int j = 0; j < 4; ++j) acc[i][j] = (f32x4)(0.f);

  const int abase = (wm * 64 + l16) * 32 + quad * 8;
  const int bbase = (wn * 64 + l16) * 32 + quad * 8;

  for (int k0 = 0; k0 < 256; k0 += 32) {
    __syncthreads();
    async_ld16(&sm.A[(r0) * 32],      gA + (size_t)(r0 + srow) * 256 + k0);
    async_ld16(&sm.A[(r0 + 16) * 32], gA + (size_t)(r0 + 16 + srow) * 256 + k0);
    async_ld16(&sm.B[(r0) * 32],      gB + (size_t)(r0 + srow) * 256 + k0);
    async_ld16(&sm.B[(r0 + 16) * 32], gB + (size_t)(r0 + 16 + srow) * 256 + k0);
    __syncthreads();
    bf16x8 af[4], bfr[4];
#pragma unroll
    for (int am = 0; am < 4; ++am) af[am] = *(const bf16x8*)&sm.A[abase + am * 16 * 32];
#pragma unroll
    for (int bn = 0; bn < 4; ++bn) bfr[bn] = *(const bf16x8*)&sm.B[bbase + bn * 16 * 32];
#pragma unroll
    for (int am = 0; am < 4; ++am)
#pragma unroll
      for (int bn = 0; bn < 4; ++bn)
        acc[am][bn] = __builtin_amdgcn_mfma_f32_16x16x32_bf16(af[am], bfr[bn], acc[am][bn], 0, 0, 0);
  }

  const float sg = sigma[0];
#pragma unroll
  for (int am = 0; am < 4; ++am) {
#pragma unroll
    for (int reg = 0; reg < 4; ++reg) {
      int m = mt * 128 + wm * 64 + am * 16 + quad * 4 + reg;
      float bias = ba[m];
      size_t rowoff = ((size_t)b * 512 + m) * 4096 + nt * 128 + wn * 64;
#pragma unroll
      for (int bn = 0; bn < 4; ++bn) {
        size_t idx = rowoff + bn * 16 + l16;
        out[idx] = X[idx] + sg * (acc[am][bn][reg] + bias);
      }
    }
  }
}

extern "C" void kernel_launch(void* const* d_in, const int* in_sizes, int n_in,
                              void* d_out, int out_size, void* d_ws, size_t ws_size,
                              hipStream_t stream) {
  (void)in_sizes; (void)n_in; (void)out_size; (void)ws_size;
  const float* X  = (const float*)d_in[0];
  const float* wt = (const float*)d_in[1];
  const float* bt = (const float*)d_in[2];
  const float* wp = (const float*)d_in[3];
  const float* bp = (const float*)d_in[4];
  const float* wg = (const float*)d_in[5];
  const float* bg = (const float*)d_in[6];
  const float* wa = (const float*)d_in[7];
  const float* ba = (const float*)d_in[8];
  const float* sg = (const float*)d_in[9];
  float* out = (float*)d_out;
  char* base = (char*)d_ws;

  unsigned short* Wcat_bf = (unsigned short*)(base);                 // 384KB
  unsigned short* Wa_bf   = (unsigned short*)(base + 0x60000);       // 256KB
  float*          bcat    = (float*)(base + 0xA0000);                // 1.5KB
  unsigned short* theta_t = (unsigned short*)(base + (1u << 20));    // 8 MiB
  unsigned short* phi_t   = (unsigned short*)(base + (9u << 20));    // 2 MiB
  unsigned short* g_t     = (unsigned short*)(base + (11u << 20));   // 8 MiB
  unsigned short* Xbf_T   = (unsigned short*)(base + (19u << 20));   // 64 MiB
  unsigned short* Obf     = (unsigned short*)(base + (19u << 20));   // 32 MiB (aliases Xbf_T; disjoint lifetime)

  pack_kernel<<<dim3(768), dim3(256), 0, stream>>>(wt, bt, wp, bp, wg, bg, wa,
                                                   Wcat_bf, bcat, Wa_bf);
  transpose_kernel<<<dim3(64, 16), dim3(256), 0, stream>>>(X, Xbf_T);
  conv_pool_kernel<<<dim3(32, 3, 16), dim3(256), 0, stream>>>(Xbf_T, Wcat_bf, bcat,
                                                              theta_t, phi_t, g_t);
  attn_kernel<<<dim3(128, 16), dim3(512), 0, stream>>>(theta_t, phi_t, g_t, Obf);
  out_kernel<<<dim3(32, 4, 16), dim3(256), 0, stream>>>(X, Obf, Wa_bf, ba, sg, out);
}

// Round 3
// 571.409 us; speedup vs baseline: 1.0091x; 1.0091x over previous
//
#include <hip/hip_runtime.h>
#include <cstdint>
#include <cstddef>

// B=16, C=512, H=W=64, HW=4096, C8=64, C2=256, M(keys)=1024

typedef float f32x4 __attribute__((ext_vector_type(4)));
typedef short bf16x8 __attribute__((ext_vector_type(8)));

static __device__ __forceinline__ float max4f(float a, float b, float c, float d) {
  return fmaxf(fmaxf(a, b), fmaxf(c, d));
}

static __device__ __forceinline__ unsigned short f2bf(float f) {
  unsigned int u = __float_as_uint(f);
  unsigned int r = u + 0x7fffu + ((u >> 16) & 1u);  // RNE
  return (unsigned short)(r >> 16);
}

// async 16B/lane global->LDS copy; lds base must be wave-uniform, HW scatters lane*16
static __device__ __forceinline__ void async_ld16(void* lds, const void* g) {
  __builtin_amdgcn_global_load_lds(
      (const __attribute__((address_space(1))) unsigned int*)g,
      (__attribute__((address_space(3))) unsigned int*)lds, 16, 0, 0);
}

// ---------------- pack weights: Wcat_bf [384][512], bcat[384] fp32, Wa_bf [512][256] ----------------
__global__ __launch_bounds__(256) void pack_kernel(
    const float* __restrict__ wt, const float* __restrict__ bt,
    const float* __restrict__ wp, const float* __restrict__ bp,
    const float* __restrict__ wg, const float* __restrict__ bg,
    const float* __restrict__ wa,
    unsigned short* __restrict__ Wcat_bf, float* __restrict__ bcat,
    unsigned short* __restrict__ Wa_bf) {
  int i = blockIdx.x * 256 + threadIdx.x;
  if (i < 384 * 512) {
    int o = i >> 9, k = i & 511;
    float v;
    if (o < 64)       v = wt[o * 512 + k];
    else if (o < 128) v = wp[(o - 64) * 512 + k];
    else              v = wg[(o - 128) * 512 + k];
    Wcat_bf[i] = f2bf(v);
  }
  if (i < 512 * 256) Wa_bf[i] = f2bf(wa[i]);
  if (i < 384) {
    float v;
    if (i < 64)       v = bt[i];
    else if (i < 128) v = bp[i - 64];
    else              v = bg[i - 128];
    bcat[i] = v;
  }
}

// ---------------- transpose/convert: X fp32 [B][512][4096] -> Xbf_T bf16 [B][4096][512] ----------------
__global__ __launch_bounds__(256) void transpose_kernel(
    const float* __restrict__ X, unsigned short* __restrict__ Xbf_T) {
  __shared__ unsigned short smT[64 * 516];
  const int b = blockIdx.y, n0 = blockIdx.x * 64;
  const int t = threadIdx.x;
  const float* Xb = X + (size_t)b * 512 * 4096;

  {
    const int nq = t & 15, kr = t >> 4;
#pragma unroll 4
    for (int it = 0; it < 32; ++it) {
      int k = it * 16 + kr;
      float4 v = *(const float4*)&Xb[(size_t)k * 4096 + n0 + nq * 4];
      smT[(nq * 4 + 0) * 516 + k] = f2bf(v.x);
      smT[(nq * 4 + 1) * 516 + k] = f2bf(v.y);
      smT[(nq * 4 + 2) * 516 + k] = f2bf(v.z);
      smT[(nq * 4 + 3) * 516 + k] = f2bf(v.w);
    }
  }
  __syncthreads();
  {
    const int c = t & 63, w = t >> 6;
#pragma unroll 4
    for (int i = 0; i < 16; ++i) {
      int n = w + 4 * i;
      const unsigned short* src = &smT[n * 516 + c * 8];
      uint2 lo = *(const uint2*)&src[0];
      uint2 hi = *(const uint2*)&src[4];
      uint4 v; v.x = lo.x; v.y = lo.y; v.z = hi.x; v.w = hi.y;
      *(uint4*)&Xbf_T[((size_t)b * 4096 + n0 + n) * 512 + c * 8] = v;
    }
  }
}

// ---------------- conv GEMM (bf16 MFMA, LDS-staged) + fused maxpool epilogue ----------------
// C[384 m][4096 n] = Wcat @ X; tile 128x128, BK=32, single-buffer global_load_lds staging.
__global__ __launch_bounds__(256, 3) void conv_pool_kernel(
    const unsigned short* __restrict__ Xbf_T, const unsigned short* __restrict__ Wcat_bf,
    const float* __restrict__ bcat,
    unsigned short* __restrict__ theta_t, unsigned short* __restrict__ phi_t,
    unsigned short* __restrict__ g_t) {
  const int b = blockIdx.z, mt = blockIdx.y, nt = blockIdx.x;
  const int n0 = nt * 128;
  __shared__ union {
    struct { unsigned short A[128 * 32]; unsigned short B[128 * 32]; } st;  // 8KB + 8KB
    float cs[64][132];                                                      // 33.8KB
  } sm;
  const int t = threadIdx.x;
  const int wave = t >> 6, lane = t & 63;
  const int wm = wave >> 1, wn = wave & 1;
  const int l16 = lane & 15, quad = lane >> 4;
  const int srow = lane >> 2, skq = (lane & 3) * 8;

  const unsigned short* gA = Wcat_bf + (size_t)(mt * 128) * 512 + skq;
  const unsigned short* gB = Xbf_T + ((size_t)b * 4096 + n0) * 512 + skq;
  const int r0 = wave * 32;

  f32x4 acc[4][4];
#pragma unroll
  for (int i = 0; i < 4; ++i)
#pragma unroll
    for (int j = 0; j < 4; ++j) acc[i][j] = (f32x4)(0.f);

  const int abase = (wm * 64 + l16) * 32 + quad * 8;
  const int bbase = (wn * 64 + l16) * 32 + quad * 8;

  for (int k0 = 0; k0 < 512; k0 += 32) {
    __syncthreads();  // prior frag reads done before overwrite
    async_ld16(&sm.st.A[(r0) * 32],      gA + (size_t)(r0 + srow) * 512 + k0);
    async_ld16(&sm.st.A[(r0 + 16) * 32], gA + (size_t)(r0 + 16 + srow) * 512 + k0);
    async_ld16(&sm.st.B[(r0) * 32],      gB + (size_t)(r0 + srow) * 512 + k0);
    async_ld16(&sm.st.B[(r0 + 16) * 32], gB + (size_t)(r0 + 16 + srow) * 512 + k0);
    __syncthreads();  // vmcnt drain -> staged data visible
    bf16x8 af[4], bfr[4];
#pragma unroll
    for (int am = 0; am < 4; ++am) af[am] = *(const bf16x8*)&sm.st.A[abase + am * 16 * 32];
#pragma unroll
    for (int bn = 0; bn < 4; ++bn) bfr[bn] = *(const bf16x8*)&sm.st.B[bbase + bn * 16 * 32];
#pragma unroll
    for (int am = 0; am < 4; ++am)
#pragma unroll
      for (int bn = 0; bn < 4; ++bn)
        acc[am][bn] = __builtin_amdgcn_mfma_f32_16x16x32_bf16(af[am], bfr[bn], acc[am][bn], 0, 0, 0);
  }
  __syncthreads();  // staging buffers dead; cs reuse safe

  // epilogue: two 64-row stripes through LDS
  for (int s = 0; s < 2; ++s) {
    const int m0 = mt * 128 + s * 64;
    if (wm == s) {
#pragma unroll
      for (int am = 0; am < 4; ++am)
#pragma unroll
        for (int bn = 0; bn < 4; ++bn)
#pragma unroll
          for (int reg = 0; reg < 4; ++reg)
            sm.cs[am * 16 + quad * 4 + reg][wn * 64 + bn * 16 + l16] =
                acc[am][bn][reg] + bcat[m0 + am * 16 + quad * 4 + reg];
    }
    __syncthreads();
    if (m0 < 64) {  // theta: -> [B][4096][64] bf16
      int col = t >> 1, half = t & 1;
      unsigned short vals[32];
#pragma unroll
      for (int i = 0; i < 32; ++i) vals[i] = f2bf(sm.cs[half * 32 + i][col]);
      unsigned short* dst = theta_t + ((size_t)b * 4096 + n0 + col) * 64 + half * 32;
#pragma unroll
      for (int j = 0; j < 4; ++j) ((uint4*)dst)[j] = ((const uint4*)vals)[j];
    } else if (m0 < 128) {  // phi: 2x2 pool -> [B][1024][64] bf16
      int px = t >> 3, ch0 = (t & 7) * 8;
      unsigned short v[8];
#pragma unroll
      for (int j = 0; j < 8; ++j) {
        int ch = ch0 + j;
        v[j] = f2bf(max4f(sm.cs[ch][2 * px], sm.cs[ch][2 * px + 1],
                          sm.cs[ch][64 + 2 * px], sm.cs[ch][64 + 2 * px + 1]));
      }
      *(uint4*)&phi_t[((size_t)b * 1024 + nt * 32 + px) * 64 + ch0] = *(const uint4*)v;
    } else {  // g: 2x2 pool -> [B][256][1024] bf16 (c-major)
      int ch = t >> 2, px0 = (t & 3) * 8;
      int gc = m0 - 128 + ch;
      unsigned short v[8];
#pragma unroll
      for (int j = 0; j < 8; ++j) {
        int px = px0 + j;
        v[j] = f2bf(max4f(sm.cs[ch][2 * px], sm.cs[ch][2 * px + 1],
                          sm.cs[ch][64 + 2 * px], sm.cs[ch][64 + 2 * px + 1]));
      }
      *(uint4*)&g_t[((size_t)b * 256 + gc) * 1024 + nt * 32 + px0] = *(const uint4*)v;
    }
    __syncthreads();
  }
}

// ---------------- fused MFMA attention: 512 threads, 8 waves ----------------
// wave w: QK over keys [128w,128w+128) for 32 queries; single stats barrier;
// P (normalized) -> bf16 LDS; PV over c-slice [32w,32w+32) x all 1024 keys.
// XCD-locality swizzle: XCD x processes ONLY batches {2x, 2x+1} so phi (128KB/b)
// and g (512KB/b) stay resident in that XCD's 4MB L2 across all 128 q-blocks.
// (R1 counters: FETCH 45MB vs 18MB compulsory -> L2 thrash at 4 batches/XCD;
//  g/phi loads at HBM latency serialized ~80x900cyc/wave = the missing 80%.)
__global__ __launch_bounds__(512, 4) void attn_kernel(
    const unsigned short* __restrict__ theta, const unsigned short* __restrict__ phi,
    const unsigned short* __restrict__ g, unsigned short* __restrict__ Obf) {
  // bijective remap of 2048 linear blocks: lin -> (b, q0)
  const int lin = blockIdx.y * gridDim.x + blockIdx.x;  // dispatch order (x fastest)
  const int xcd = lin & 7;
  const int s_ = lin >> 3;              // 0..255 per XCD
  const int b = xcd * 2 + (s_ & 1);     // 2 batches per XCD
  const int q0 = (s_ >> 1) * 32;        // 128 q-blocks per batch
  __shared__ unsigned short S_s[32][1032];  // 66 KB
  __shared__ float2 sstat[32][8];           // (m_w, sum_w) per q-row per wave
  const int t = threadIdx.x;
  const int w = t >> 6, lane = t & 63;
  const int l16 = lane & 15, quad = lane >> 4;
  const int m0w = w * 128;

  // A-frags: theta[32 q][64 c]
  bf16x8 afrag[2][2];
#pragma unroll
  for (int qt = 0; qt < 2; ++qt)
#pragma unroll
    for (int kh = 0; kh < 2; ++kh)
      afrag[qt][kh] = *(const bf16x8*)&theta[((size_t)b * 4096 + q0 + qt * 16 + l16) * 64 +
                                             kh * 32 + quad * 8];

  // ---- QK^T: S[32 q][128 m] per wave ----
  f32x4 acc[2][8];
#pragma unroll
  for (int qt = 0; qt < 2; ++qt)
#pragma unroll
    for (int mt = 0; mt < 8; ++mt) acc[qt][mt] = (f32x4)(0.f);

  const unsigned short* phiB = phi + (size_t)b * 1024 * 64;
#pragma unroll
  for (int mt = 0; mt < 8; ++mt) {
    int m = m0w + mt * 16 + l16;
    bf16x8 b0 = *(const bf16x8*)&phiB[(size_t)m * 64 + quad * 8];
    bf16x8 b1 = *(const bf16x8*)&phiB[(size_t)m * 64 + 32 + quad * 8];
#pragma unroll
    for (int qt = 0; qt < 2; ++qt) {
      acc[qt][mt] = __builtin_amdgcn_mfma_f32_16x16x32_bf16(afrag[qt][0], b0, acc[qt][mt], 0, 0, 0);
      acc[qt][mt] = __builtin_amdgcn_mfma_f32_16x16x32_bf16(afrag[qt][1], b1, acc[qt][mt], 0, 0, 0);
    }
  }

  // ---- per-wave max & exp-sum (rows: q = qt*16 + quad*4 + reg) ----
  float mx8[8], sum8[8];
#pragma unroll
  for (int r = 0; r < 8; ++r) {
    int qt = r >> 2, reg = r & 3;
    float m = acc[qt][0][reg];
#pragma unroll
    for (int mt = 1; mt < 8; ++mt) m = fmaxf(m, acc[qt][mt][reg]);
#pragma unroll
    for (int d = 1; d < 16; d <<= 1) m = fmaxf(m, __shfl_xor(m, d));
    mx8[r] = m;
    sum8[r] = 0.f;
  }
#pragma unroll
  for (int qt = 0; qt < 2; ++qt)
#pragma unroll
    for (int mt = 0; mt < 8; ++mt)
#pragma unroll
      for (int reg = 0; reg < 4; ++reg) {
        int r = qt * 4 + reg;
        float p = __expf(acc[qt][mt][reg] - mx8[r]);
        acc[qt][mt][reg] = p;
        sum8[r] += p;
      }
#pragma unroll
  for (int r = 0; r < 8; ++r) {
#pragma unroll
    for (int d = 1; d < 16; d <<= 1) sum8[r] += __shfl_xor(sum8[r], d);
  }
  if (l16 == 0) {
#pragma unroll
    for (int r = 0; r < 8; ++r) {
      int q = (r >> 2) * 16 + quad * 4 + (r & 3);
      sstat[q][w] = make_float2(mx8[r], sum8[r]);
    }
  }
  __syncthreads();  // single stats barrier

  // ---- global stats + normalized P write ----
  float alpha[8];
#pragma unroll
  for (int r = 0; r < 8; ++r) {
    int q = (r >> 2) * 16 + quad * 4 + (r & 3);
    float2 st[8];
#pragma unroll
    for (int j = 0; j < 4; ++j) ((float4*)st)[j] = *(const float4*)&sstat[q][j * 2];
    float mg = st[0].x;
#pragma unroll
    for (int j = 1; j < 8; ++j) mg = fmaxf(mg, st[j].x);
    float sg = 0.f;
#pragma unroll
    for (int j = 0; j < 8; ++j) sg += st[j].y * __expf(st[j].x - mg);
    alpha[r] = __expf(mx8[r] - mg) / sg;
  }
#pragma unroll
  for (int qt = 0; qt < 2; ++qt)
#pragma unroll
    for (int mt = 0; mt < 8; ++mt)
#pragma unroll
      for (int reg = 0; reg < 4; ++reg) {
        int q = qt * 16 + quad * 4 + reg;
        S_s[q][m0w + mt * 16 + l16] = f2bf(acc[qt][mt][reg] * alpha[qt * 4 + reg]);
      }
  __syncthreads();

  // ---- PV: O[32 q][32 c] per wave over all 1024 keys ----
  const int cbase = w * 32;
  f32x4 accO[2][2];
#pragma unroll
  for (int qt = 0; qt < 2; ++qt)
#pragma unroll
    for (int ct = 0; ct < 2; ++ct) accO[qt][ct] = (f32x4)(0.f);
  const unsigned short* gB = g + (size_t)b * 256 * 1024;
  for (int k0 = 0; k0 < 1024; k0 += 32) {
    bf16x8 a0 = *(const bf16x8*)&S_s[l16][k0 + quad * 8];
    bf16x8 a1 = *(const bf16x8*)&S_s[16 + l16][k0 + quad * 8];
#pragma unroll
    for (int ct = 0; ct < 2; ++ct) {
      bf16x8 bb = *(const bf16x8*)&gB[(size_t)(cbase + ct * 16 + l16) * 1024 + k0 + quad * 8];
      accO[0][ct] = __builtin_amdgcn_mfma_f32_16x16x32_bf16(a0, bb, accO[0][ct], 0, 0, 0);
      accO[1][ct] = __builtin_amdgcn_mfma_f32_16x16x32_bf16(a1, bb, accO[1][ct], 0, 0, 0);
    }
  }
  unsigned short* Ob = Obf + ((size_t)b * 4096 + q0) * 256;
#pragma unroll
  for (int qt = 0; qt < 2; ++qt)
#pragma unroll
    for (int ct = 0; ct < 2; ++ct)
#pragma unroll
      for (int reg = 0; reg < 4; ++reg)
        Ob[(size_t)(qt * 16 + quad * 4 + reg) * 256 + cbase + ct * 16 + l16] =
            f2bf(accO[qt][ct][reg]);
}

// ---------------- final conv (bf16 MFMA, LDS-staged) + residual ----------------
__global__ __launch_bounds__(256, 3) void out_kernel(
    const float* __restrict__ X, const unsigned short* __restrict__ Obf,
    const unsigned short* __restrict__ Wa_bf, const float* __restrict__ ba,
    const float* __restrict__ sigma, float* __restrict__ out) {
  const int b = blockIdx.z, mt = blockIdx.y, nt = blockIdx.x;
  __shared__ struct { unsigned short A[128 * 32]; unsigned short B[128 * 32]; } sm;
  const int t = threadIdx.x;
  const int wave = t >> 6, lane = t & 63;
  const int wm = wave >> 1, wn = wave & 1;
  const int l16 = lane & 15, quad = lane >> 4;
  const int srow = lane >> 2, skq = (lane & 3) * 8;

  const unsigned short* gA = Wa_bf + (size_t)(mt * 128) * 256 + skq;
  const unsigned short* gB = Obf + ((size_t)b * 4096 + nt * 128) * 256 + skq;
  const int r0 = wave * 32;

  f32x4 acc[4][4];
#pragma unroll
  for (int i = 0; i < 4; ++i)
#pragma unroll
    for (int j = 0; j < 4; ++j) acc[i][j] = (f32x4)(0.f);

  const int abase = (wm * 64 + l16) * 32 + quad * 8;
  const int bbase = (wn * 64 + l16) * 32 + quad * 8;

  for (int k0 = 0; k0 < 256; k0 += 32) {
    __syncthreads();
    async_ld16(&sm.A[(r0) * 32],      gA + (size_t)(r0 + srow) * 256 + k0);
    async_ld16(&sm.A[(r0 + 16) * 32], gA + (size_t)(r0 + 16 + srow) * 256 + k0);
    async_ld16(&sm.B[(r0) * 32],      gB + (size_t)(r0 + srow) * 256 + k0);
    async_ld16(&sm.B[(r0 + 16) * 32], gB + (size_t)(r0 + 16 + srow) * 256 + k0);
    __syncthreads();
    bf16x8 af[4], bfr[4];
#pragma unroll
    for (int am = 0; am < 4; ++am) af[am] = *(const bf16x8*)&sm.A[abase + am * 16 * 32];
#pragma unroll
    for (int bn = 0; bn < 4; ++bn) bfr[bn] = *(const bf16x8*)&sm.B[bbase + bn * 16 * 32];
#pragma unroll
    for (int am = 0; am < 4; ++am)
#pragma unroll
      for (int bn = 0; bn < 4; ++bn)
        acc[am][bn] = __builtin_amdgcn_mfma_f32_16x16x32_bf16(af[am], bfr[bn], acc[am][bn], 0, 0, 0);
  }

  const float sg = sigma[0];
#pragma unroll
  for (int am = 0; am < 4; ++am) {
#pragma unroll
    for (int reg = 0; reg < 4; ++reg) {
      int m = mt * 128 + wm * 64 + am * 16 + quad * 4 + reg;
      float bias = ba[m];
      size_t rowoff = ((size_t)b * 512 + m) * 4096 + nt * 128 + wn * 64;
#pragma unroll
      for (int bn = 0; bn < 4; ++bn) {
        size_t idx = rowoff + bn * 16 + l16;
        out[idx] = X[idx] + sg * (acc[am][bn][reg] + bias);
      }
    }
  }
}

extern "C" void kernel_launch(void* const* d_in, const int* in_sizes, int n_in,
                              void* d_out, int out_size, void* d_ws, size_t ws_size,
                              hipStream_t stream) {
  (void)in_sizes; (void)n_in; (void)out_size; (void)ws_size;
  const float* X  = (const float*)d_in[0];
  const float* wt = (const float*)d_in[1];
  const float* bt = (const float*)d_in[2];
  const float* wp = (const float*)d_in[3];
  const float* bp = (const float*)d_in[4];
  const float* wg = (const float*)d_in[5];
  const float* bg = (const float*)d_in[6];
  const float* wa = (const float*)d_in[7];
  const float* ba = (const float*)d_in[8];
  const float* sg = (const float*)d_in[9];
  float* out = (float*)d_out;
  char* base = (char*)d_ws;

  unsigned short* Wcat_bf = (unsigned short*)(base);                 // 384KB
  unsigned short* Wa_bf   = (unsigned short*)(base + 0x60000);       // 256KB
  float*          bcat    = (float*)(base + 0xA0000);                // 1.5KB
  unsigned short* theta_t = (unsigned short*)(base + (1u << 20));    // 8 MiB
  unsigned short* phi_t   = (unsigned short*)(base + (9u << 20));    // 2 MiB
  unsigned short* g_t     = (unsigned short*)(base + (11u << 20));   // 8 MiB
  unsigned short* Xbf_T   = (unsigned short*)(base + (19u << 20));   // 64 MiB
  unsigned short* Obf     = (unsigned short*)(base + (19u << 20));   // 32 MiB (aliases Xbf_T; disjoint lifetime)

  pack_kernel<<<dim3(768), dim3(256), 0, stream>>>(wt, bt, wp, bp, wg, bg, wa,
                                                   Wcat_bf, bcat, Wa_bf);
  transpose_kernel<<<dim3(64, 16), dim3(256), 0, stream>>>(X, Xbf_T);
  conv_pool_kernel<<<dim3(32, 3, 16), dim3(256), 0, stream>>>(Xbf_T, Wcat_bf, bcat,
                                                              theta_t, phi_t, g_t);
  attn_kernel<<<dim3(128, 16), dim3(512), 0, stream>>>(theta_t, phi_t, g_t, Obf);
  out_kernel<<<dim3(32, 4, 16), dim3(256), 0, stream>>>(X, Obf, Wa_bf, ba, sg, out);
}